// Round 4
// baseline (403.727 us; speedup 1.0000x reference)
//
#include <hip/hip_runtime.h>

#define BB 8
#define NN 128
#define CC 64
#define LL 3
#define HH 128
#define NEG 0.01f
#define NPOS (BB*NN*NN)   // 131072

typedef __attribute__((ext_vector_type(8))) short shortx8;   // 8 bf16 = 4 VGPRs
typedef __attribute__((ext_vector_type(4))) float f32x4;

// ---- workspace layout (float offsets) ----
#define OFF_HHI   0L          // h hi: 131072*64 shorts = 4194304 floats
#define OFF_HLO   4194304L    // h lo
#define OFF_XN    8388608L    // inter-layer x (bf16): 4194304 floats
#define OFF_RS    12582912L   // rowsum fp32 [1024][64]
#define OFF_DG    12648448L   // diag fp32 [1024][64]
#define OFF_RCDH  12713984L   // RCD hi [1024][192] shorts = 98304 floats
#define OFF_RCDL  12812288L
#define OFF_UB    12910592L   // Ubias [8][64]
#define OFF_DB    12911104L   // Dbias [8][64]
#define OFF_U     12911616L   // [1024][64]
#define OFF_V     12977152L
#define OFF_D     13042688L
#define OFF_SB    13108224L   // bf16 const region (shorts)
// sb short offsets: wb1@0 (L*128*64), wb2@24576 (L*128*128), wb3@73728 (L*64*128),
//   c9h@98304, c9l@110592, c10h@122880, c10l@135168 (each L*64*64, [l][s][d]),
//   Kh@147456, Kl@258048 (each L*192*192, [l][out][k])
// total ~13.3M floats ≈ 53 MB

__device__ __forceinline__ float leaky(float v) { return v >= 0.f ? v : NEG * v; }

__device__ __forceinline__ short f2bf(float f) {   // RNE float -> bf16
    unsigned u = __builtin_bit_cast(unsigned, f);
    u += 0x7fff + ((u >> 16) & 1);
    return (short)(u >> 16);
}
__device__ __forceinline__ float bf2f(short s) {
    unsigned u = ((unsigned)(unsigned short)s) << 16;
    return __builtin_bit_cast(float, u);
}
__device__ __forceinline__ unsigned pkf(float a, float b) {  // two f32 -> packed bf16x2
    return (unsigned)(unsigned short)f2bf(a) | ((unsigned)(unsigned short)f2bf(b) << 16);
}
__device__ __forceinline__ unsigned pks(short a, short b) {
    return (unsigned)(unsigned short)a | ((unsigned)(unsigned short)b << 16);
}

// ---------------- prep: bf16 weights, split c9/c10 [s][d], split K-matrix [out][k] ----------------
__global__ void prep_kernel(const float* __restrict__ w1, const float* __restrict__ w2,
                            const float* __restrict__ w3, const float* __restrict__ coefs,
                            float* __restrict__ ws) {
    long idx = (long)blockIdx.x * 256 + threadIdx.x;
    short* sb = (short*)(ws + OFF_SB);
    if (idx < 24576) {                       // wb1[l][h][c]
        sb[idx] = f2bf(w1[idx]);
    } else if (idx < 73728) {                // wb2[l][h][k]
        sb[idx] = f2bf(w2[idx - 24576]);
    } else if (idx < 98304) {                // wb3[l][c][k]
        sb[idx] = f2bf(w3[idx - 73728]);
    } else if (idx < 110592) {               // c9 hi/lo [l][s][d]
        long r = idx - 98304; int l = (int)(r / 4096); int q = (int)(r % 4096);
        int s = q >> 6, d = q & 63;
        float v = coefs[(((long)l*CC + d)*CC + s)*15 + 9];
        short hi = f2bf(v);
        sb[98304 + r]  = hi;
        sb[110592 + r] = f2bf(v - bf2f(hi));
    } else if (idx < 122880) {               // c10 hi/lo [l][s][d]
        long r = idx - 110592; int l = (int)(r / 4096); int q = (int)(r % 4096);
        int s = q >> 6, d = q & 63;
        float v = coefs[(((long)l*CC + d)*CC + s)*15 + 10];
        short hi = f2bf(v);
        sb[122880 + r] = hi;
        sb[135168 + r] = f2bf(v - bf2f(hi));
    } else if (idx < 233472) {               // Kbig hi/lo [l][out 192][k 192]
        long r = idx - 122880;
        int l = (int)(r / 36864); int q = (int)(r % 36864);
        int o = q / 192, k = q % 192;
        int wo = o >> 6, s = o & 63, wk = k >> 6, d = k & 63;
        // out-block {U,V,D} x k-block {cs,rs,dg} -> coef index
        const int sel[3][3] = {{5,6,11},{7,8,12},{3,2,0}};
        float v = coefs[(((long)l*CC + d)*CC + s)*15 + sel[wo][wk]];
        short hi = f2bf(v);
        sb[147456 + r] = hi;
        sb[258048 + r] = f2bf(v - bf2f(hi));
    }
}

// ---------------- MFMA fused 3-stage MLP (swapped operands: W = A-frag, x = B-frag) ------------
// D-frag: lane holds 4 consecutive OUT channels at one position -> packed 8B stores.
// LDS: xt@0 (64x64 bf16, 128B rows, swz), h1@8192 (64x128, 256B rows), h2@24576.
__global__ __launch_bounds__(256, 4) void mlp_kernel(
    const float* __restrict__ xf, const short* __restrict__ xb,
    const float* __restrict__ mask,
    const float* __restrict__ b1, const float* __restrict__ b2, const float* __restrict__ b3,
    const short* __restrict__ wb1, const short* __restrict__ wb2, const short* __restrict__ wb3,
    short* __restrict__ hhi, short* __restrict__ hlo)
{
    __shared__ __align__(16) char lds[40960];
    const int t = threadIdx.x;
    const int lane = t & 63;
    const int w = t >> 6;
    const int arow = lane & 15;
    const int kgrp = lane >> 4;
    const long pos0 = (long)blockIdx.x * 64;

    if (xb == nullptr) {
        // stage fp32 x -> bf16 LDS tile [pos][64]
        const int row = t >> 2, q = t & 3;
        const float4* src = (const float4*)(xf + (pos0 + row)*CC + q*16);
        short sv[16];
        #pragma unroll
        for (int i = 0; i < 4; ++i) {
            float4 v = src[i];
            sv[i*4+0] = f2bf(v.x); sv[i*4+1] = f2bf(v.y);
            sv[i*4+2] = f2bf(v.z); sv[i*4+3] = f2bf(v.w);
        }
        const int swz = (row & 7) << 4;
        *(shortx8*)(&lds[row*128 + ((q*32 +  0) ^ swz)]) = *(shortx8*)(&sv[0]);
        *(shortx8*)(&lds[row*128 + ((q*32 + 16) ^ swz)]) = *(shortx8*)(&sv[8]);
        __syncthreads();
    }

    // ---- stage 1: 128 outs; wave w -> [w*32, w*32+32) ----
    {
        f32x4 acc[2][4];
        #pragma unroll
        for (int of = 0; of < 2; ++of)
            #pragma unroll
            for (int pf = 0; pf < 4; ++pf) acc[of][pf] = (f32x4){0.f,0.f,0.f,0.f};
        #pragma unroll
        for (int kk = 0; kk < 2; ++kk) {
            shortx8 bx[4];
            #pragma unroll
            for (int pf = 0; pf < 4; ++pf) {
                if (xb) {
                    bx[pf] = *(const shortx8*)(xb + (pos0 + pf*16 + arow)*CC + kk*32 + kgrp*8);
                } else {
                    const int p = pf*16 + arow;
                    bx[pf] = *(const shortx8*)(&lds[p*128 + ((kk*64 + kgrp*16) ^ ((p & 7) << 4))]);
                }
            }
            #pragma unroll
            for (int of = 0; of < 2; ++of) {
                const shortx8 a = *(const shortx8*)(wb1 + (long)(w*32 + of*16 + arow)*CC + kk*32 + kgrp*8);
                #pragma unroll
                for (int pf = 0; pf < 4; ++pf)
                    acc[of][pf] = __builtin_amdgcn_mfma_f32_16x16x32_bf16(a, bx[pf], acc[of][pf], 0, 0, 0);
            }
        }
        #pragma unroll
        for (int of = 0; of < 2; ++of) {
            const int o0 = w*32 + of*16 + kgrp*4;
            const float4 bv = *(const float4*)(b1 + o0);
            #pragma unroll
            for (int pf = 0; pf < 4; ++pf) {
                const int p = pf*16 + arow;
                unsigned u0 = pkf(leaky(acc[of][pf][0] + bv.x), leaky(acc[of][pf][1] + bv.y));
                unsigned u1 = pkf(leaky(acc[of][pf][2] + bv.z), leaky(acc[of][pf][3] + bv.w));
                *(uint2*)(&lds[8192 + p*256 + ((o0*2) ^ ((p & 7) << 4))]) = make_uint2(u0, u1);
            }
        }
    }
    __syncthreads();

    // ---- stage 2: 128 outs; wave w -> [w*32, w*32+32) ----
    {
        f32x4 acc[2][4];
        #pragma unroll
        for (int of = 0; of < 2; ++of)
            #pragma unroll
            for (int pf = 0; pf < 4; ++pf) acc[of][pf] = (f32x4){0.f,0.f,0.f,0.f};
        #pragma unroll
        for (int kk = 0; kk < 4; ++kk) {
            shortx8 bx[4];
            #pragma unroll
            for (int pf = 0; pf < 4; ++pf) {
                const int p = pf*16 + arow;
                bx[pf] = *(const shortx8*)(&lds[8192 + p*256 + ((kk*64 + kgrp*16) ^ ((p & 7) << 4))]);
            }
            #pragma unroll
            for (int of = 0; of < 2; ++of) {
                const shortx8 a = *(const shortx8*)(wb2 + (long)(w*32 + of*16 + arow)*HH + kk*32 + kgrp*8);
                #pragma unroll
                for (int pf = 0; pf < 4; ++pf)
                    acc[of][pf] = __builtin_amdgcn_mfma_f32_16x16x32_bf16(a, bx[pf], acc[of][pf], 0, 0, 0);
            }
        }
        #pragma unroll
        for (int of = 0; of < 2; ++of) {
            const int o0 = w*32 + of*16 + kgrp*4;
            const float4 bv = *(const float4*)(b2 + o0);
            #pragma unroll
            for (int pf = 0; pf < 4; ++pf) {
                const int p = pf*16 + arow;
                unsigned u0 = pkf(leaky(acc[of][pf][0] + bv.x), leaky(acc[of][pf][1] + bv.y));
                unsigned u1 = pkf(leaky(acc[of][pf][2] + bv.z), leaky(acc[of][pf][3] + bv.w));
                *(uint2*)(&lds[24576 + p*256 + ((o0*2) ^ ((p & 7) << 4))]) = make_uint2(u0, u1);
            }
        }
    }
    __syncthreads();

    // ---- stage 3: 64 outs; wave w -> [w*16, w*16+16); direct split-bf16 global store ----
    {
        f32x4 acc[4];
        #pragma unroll
        for (int pf = 0; pf < 4; ++pf) acc[pf] = (f32x4){0.f,0.f,0.f,0.f};
        #pragma unroll
        for (int kk = 0; kk < 4; ++kk) {
            const shortx8 a = *(const shortx8*)(wb3 + (long)(w*16 + arow)*HH + kk*32 + kgrp*8);
            #pragma unroll
            for (int pf = 0; pf < 4; ++pf) {
                const int p = pf*16 + arow;
                const shortx8 bx = *(const shortx8*)(&lds[24576 + p*256 + ((kk*64 + kgrp*16) ^ ((p & 7) << 4))]);
                acc[pf] = __builtin_amdgcn_mfma_f32_16x16x32_bf16(a, bx, acc[pf], 0, 0, 0);
            }
        }
        const int o0 = w*16 + kgrp*4;
        const float4 bv = *(const float4*)(b3 + o0);
        #pragma unroll
        for (int pf = 0; pf < 4; ++pf) {
            const int p = pf*16 + arow;
            const long pos = pos0 + p;
            const float mv = mask[pos];
            short hi[4], lo[4];
            float vals[4] = {acc[pf][0] + bv.x, acc[pf][1] + bv.y, acc[pf][2] + bv.z, acc[pf][3] + bv.w};
            #pragma unroll
            for (int r = 0; r < 4; ++r) {
                float v = leaky(vals[r]) * mv;
                hi[r] = f2bf(v);
                lo[r] = f2bf(v - bf2f(hi[r]));
            }
            *(uint2*)(hhi + pos*CC + o0) = make_uint2(pks(hi[0], hi[1]), pks(hi[2], hi[3]));
            *(uint2*)(hlo + pos*CC + o0) = make_uint2(pks(lo[0], lo[1]), pks(lo[2], lo[3]));
        }
    }
}

// ---------------- reductions: rowsum, colsum, diag (reads split h; emits fp32 + split RCD) ----
__global__ __launch_bounds__(256) void reduce_kernel(const short* __restrict__ hhi,
                                                     const short* __restrict__ hlo,
                                                     float* __restrict__ rowsum,
                                                     float* __restrict__ diag,
                                                     short* __restrict__ rcdh,
                                                     short* __restrict__ rcdl) {
    const int br = blockIdx.x;            // n*128 + r
    const int n = br >> 7, r = br & 127;
    const int t = threadIdx.x, c = t & 63, g = t >> 6;
    __shared__ float red[4][64];
    const long rowbase = ((long)(n*NN + r) * NN) * CC;
    float acc = 0.f;
    for (int j = g; j < NN; j += 4) {
        long idx = rowbase + (long)j*CC + c;
        acc += bf2f(hhi[idx]) + bf2f(hlo[idx]);
    }
    red[g][c] = acc;
    __syncthreads();
    if (t < 64) {
        float rs = red[0][c] + red[1][c] + red[2][c] + red[3][c];
        rowsum[(long)br*CC + c] = rs;
        short h = f2bf(rs);
        rcdh[(long)br*192 + 64 + c] = h;
        rcdl[(long)br*192 + 64 + c] = f2bf(rs - bf2f(h));
    }
    __syncthreads();
    const long colbase = ((long)n*NN*NN + r) * CC;
    float acc2 = 0.f;
    for (int i = g; i < NN; i += 4) {
        long idx = colbase + (long)i*NN*CC + c;
        acc2 += bf2f(hhi[idx]) + bf2f(hlo[idx]);
    }
    red[g][c] = acc2;
    __syncthreads();
    if (t < 64) {
        float cs = red[0][c] + red[1][c] + red[2][c] + red[3][c];
        short h = f2bf(cs);
        rcdh[(long)br*192 + c] = h;
        rcdl[(long)br*192 + c] = f2bf(cs - bf2f(h));
        long didx = rowbase + (long)r*CC + c;
        float dg = bf2f(hhi[didx]) + bf2f(hlo[didx]);
        diag[(long)br*CC + c] = dg;
        short hd = f2bf(dg);
        rcdh[(long)br*192 + 128 + c] = hd;
        rcdl[(long)br*192 + 128 + c] = f2bf(dg - bf2f(hd));
    }
}

// ---------------- trace/total -> per-n biases for U and D ----------------
__global__ __launch_bounds__(256) void tt_kernel(const float* __restrict__ rowsum,
                                                 const float* __restrict__ diag,
                                                 const float* __restrict__ coefs, int layer,
                                                 float* __restrict__ ubias,
                                                 float* __restrict__ dbias) {
    const int n = blockIdx.x;
    const int t = threadIdx.x, c = t & 63, g = t >> 6;
    __shared__ float ra[4][64], rb[4][64];
    __shared__ float trS[64], ttS[64];
    float a = 0.f, b = 0.f;
    for (int i = g; i < NN; i += 4) {
        a += rowsum[((long)n*NN + i)*CC + c];
        b += diag[((long)n*NN + i)*CC + c];
    }
    ra[g][c] = a; rb[g][c] = b;
    __syncthreads();
    if (t < 64) {
        ttS[c] = ra[0][c] + ra[1][c] + ra[2][c] + ra[3][c];
        trS[c] = rb[0][c] + rb[1][c] + rb[2][c] + rb[3][c];
    }
    __syncthreads();
    if (t < 128) {
        const int which = t >> 6, s = t & 63;
        const float* cf = coefs + (long)layer*CC*CC*15;
        float acc = 0.f;
        for (int d = 0; d < CC; ++d) {
            const float* cds = cf + ((long)d*CC + s)*15;
            if (which == 0) acc += cds[13]*trS[d] + cds[14]*ttS[d];
            else            acc += cds[1]*trS[d] + cds[4]*ttS[d];
        }
        if (which == 0) ubias[n*CC + s] = acc;
        else            dbias[n*CC + s] = acc;
    }
}

// ---------------- U/V/D via MFMA: [1024 rows x 192 k] RCD x K[192 out x 192 k] ----------------
__global__ __launch_bounds__(256) void uvd_kernel(
    const short* __restrict__ rcdh, const short* __restrict__ rcdl,
    const short* __restrict__ kh, const short* __restrict__ kl,
    const float* __restrict__ ubias, const float* __restrict__ dbias,
    float* __restrict__ U, float* __restrict__ V, float* __restrict__ D)
{
    const int t = threadIdx.x, lane = t & 63, w = t >> 6;
    const int arow = lane & 15, kgrp = lane >> 4;
    const int r0 = blockIdx.x * 64;
    f32x4 acc[3][4];
    #pragma unroll
    for (int o = 0; o < 3; ++o)
        #pragma unroll
        for (int pf = 0; pf < 4; ++pf) acc[o][pf] = (f32x4){0.f,0.f,0.f,0.f};
    #pragma unroll
    for (int kk = 0; kk < 6; ++kk) {
        shortx8 bh[4], bl[4];
        #pragma unroll
        for (int pf = 0; pf < 4; ++pf) {
            const long off = (long)(r0 + pf*16 + arow)*192 + kk*32 + kgrp*8;
            bh[pf] = *(const shortx8*)(rcdh + off);
            bl[pf] = *(const shortx8*)(rcdl + off);
        }
        #pragma unroll
        for (int o = 0; o < 3; ++o) {
            const long aoff = (long)((w*3 + o)*16 + arow)*192 + kk*32 + kgrp*8;
            const shortx8 ah = *(const shortx8*)(kh + aoff);
            const shortx8 al = *(const shortx8*)(kl + aoff);
            #pragma unroll
            for (int pf = 0; pf < 4; ++pf) {
                acc[o][pf] = __builtin_amdgcn_mfma_f32_16x16x32_bf16(ah, bh[pf], acc[o][pf], 0, 0, 0);
                acc[o][pf] = __builtin_amdgcn_mfma_f32_16x16x32_bf16(ah, bl[pf], acc[o][pf], 0, 0, 0);
                acc[o][pf] = __builtin_amdgcn_mfma_f32_16x16x32_bf16(al, bh[pf], acc[o][pf], 0, 0, 0);
            }
        }
    }
    #pragma unroll
    for (int o = 0; o < 3; ++o) {
        const int o16 = (w*3 + o)*16;
        const int o0 = o16 + kgrp*4;
        #pragma unroll
        for (int pf = 0; pf < 4; ++pf) {
            const long rr = r0 + pf*16 + arow;
            const int n = (int)(rr >> 7);
            float4 a = make_float4(acc[o][pf][0], acc[o][pf][1], acc[o][pf][2], acc[o][pf][3]);
            if (o16 < 64) {
                const float4 ub = *(const float4*)(ubias + n*CC + o0);
                a.x += ub.x; a.y += ub.y; a.z += ub.z; a.w += ub.w;
                *(float4*)(U + rr*CC + o0) = a;
            } else if (o16 < 128) {
                *(float4*)(V + rr*CC + (o0 - 64)) = a;
            } else {
                const float4 db = *(const float4*)(dbias + n*CC + (o0 - 128));
                a.x += db.x; a.y += db.y; a.z += db.z; a.w += db.w;
                *(float4*)(D + rr*CC + (o0 - 128)) = a;
            }
        }
    }
}

// ---------------- Eq2to2: zero-LDS, direct-global split-bf16 B-frags, swapped operands ----------
__global__ __launch_bounds__(256) void eq_kernel(
    const short* __restrict__ hhi, const short* __restrict__ hlo,
    const float* __restrict__ mask,
    const short* __restrict__ c9h, const short* __restrict__ c9l,
    const short* __restrict__ c10h, const short* __restrict__ c10l,
    const float* __restrict__ U, const float* __restrict__ V, const float* __restrict__ D,
    const float* __restrict__ bias, const float* __restrict__ idbias,
    float* __restrict__ outf, short* __restrict__ outb)
{
    const int t = threadIdx.x, lane = t & 63, w = t >> 6;
    const int arow = lane & 15, kgrp = lane >> 4;
    const int jt = blockIdx.x, it = blockIdx.y, n = blockIdx.z;
    const int i0 = it*8, j0 = jt*8;
    const int s0 = w*16;

    f32x4 acc[4];
    #pragma unroll
    for (int pf = 0; pf < 4; ++pf) acc[pf] = (f32x4){0.f,0.f,0.f,0.f};

    #pragma unroll
    for (int kk = 0; kk < 2; ++kk) {
        const long co = (long)(s0 + arow)*CC + kk*32 + kgrp*8;
        const shortx8 a9h  = *(const shortx8*)(c9h  + co);
        const shortx8 a9l  = *(const shortx8*)(c9l  + co);
        const shortx8 a10h = *(const shortx8*)(c10h + co);
        const shortx8 a10l = *(const shortx8*)(c10l + co);
        #pragma unroll
        for (int pf = 0; pf < 4; ++pf) {
            const int p = pf*16 + arow;
            const int pi = i0 + (p >> 3), pj = j0 + (p & 7);
            const long posA = ((long)n*NN + pi)*NN + pj;
            const long posT = ((long)n*NN + pj)*NN + pi;
            const long ka = posA*CC + kk*32 + kgrp*8;
            const long kt = posT*CC + kk*32 + kgrp*8;
            const shortx8 bAh = *(const shortx8*)(hhi + ka);
            const shortx8 bAl = *(const shortx8*)(hlo + ka);
            const shortx8 bTh = *(const shortx8*)(hhi + kt);
            const shortx8 bTl = *(const shortx8*)(hlo + kt);
            acc[pf] = __builtin_amdgcn_mfma_f32_16x16x32_bf16(a9h,  bAh, acc[pf], 0, 0, 0);
            acc[pf] = __builtin_amdgcn_mfma_f32_16x16x32_bf16(a9h,  bAl, acc[pf], 0, 0, 0);
            acc[pf] = __builtin_amdgcn_mfma_f32_16x16x32_bf16(a9l,  bAh, acc[pf], 0, 0, 0);
            acc[pf] = __builtin_amdgcn_mfma_f32_16x16x32_bf16(a10h, bTh, acc[pf], 0, 0, 0);
            acc[pf] = __builtin_amdgcn_mfma_f32_16x16x32_bf16(a10h, bTl, acc[pf], 0, 0, 0);
            acc[pf] = __builtin_amdgcn_mfma_f32_16x16x32_bf16(a10l, bTh, acc[pf], 0, 0, 0);
        }
    }

    const int sc = s0 + kgrp*4;
    const float4 bv = *(const float4*)(bias + sc);
    #pragma unroll
    for (int pf = 0; pf < 4; ++pf) {
        const int p = pf*16 + arow;
        const int pi = i0 + (p >> 3), pj = j0 + (p & 7);
        const long pix = ((long)n*NN + pi)*NN + pj;
        const float4 u4 = *(const float4*)(U + ((long)n*NN + pi)*CC + sc);
        const float4 v4 = *(const float4*)(V + ((long)n*NN + pj)*CC + sc);
        float vv[4];
        vv[0] = acc[pf][0] + u4.x + v4.x + bv.x;
        vv[1] = acc[pf][1] + u4.y + v4.y + bv.y;
        vv[2] = acc[pf][2] + u4.z + v4.z + bv.z;
        vv[3] = acc[pf][3] + u4.w + v4.w + bv.w;
        if (it == jt) {
            if (pi == pj) {
                const float4 d4  = *(const float4*)(D + ((long)n*NN + pi)*CC + sc);
                const float4 db4 = *(const float4*)(idbias + sc);
                vv[0] += d4.x + db4.x; vv[1] += d4.y + db4.y;
                vv[2] += d4.z + db4.z; vv[3] += d4.w + db4.w;
            }
        }
        const float mv = mask[pix];
        #pragma unroll
        for (int r = 0; r < 4; ++r) vv[r] = leaky(vv[r]) * mv;
        if (outf) {
            *(float4*)(outf + pix*CC + sc) = make_float4(vv[0], vv[1], vv[2], vv[3]);
        } else {
            *(uint2*)(outb + pix*CC + sc) = make_uint2(pkf(vv[0], vv[1]), pkf(vv[2], vv[3]));
        }
    }
}

extern "C" void kernel_launch(void* const* d_in, const int* in_sizes, int n_in,
                              void* d_out, int out_size, void* d_ws, size_t ws_size,
                              hipStream_t stream) {
    const float* x     = (const float*)d_in[0];
    const float* mask  = (const float*)d_in[1];
    const float* w1    = (const float*)d_in[2];
    const float* b1    = (const float*)d_in[3];
    const float* w2    = (const float*)d_in[4];
    const float* b2    = (const float*)d_in[5];
    const float* w3    = (const float*)d_in[6];
    const float* b3    = (const float*)d_in[7];
    const float* coefs = (const float*)d_in[8];
    const float* bias  = (const float*)d_in[9];
    const float* idb   = (const float*)d_in[10];
    float* out = (float*)d_out;
    float* ws  = (float*)d_ws;

    short* hhi   = (short*)(ws + OFF_HHI);
    short* hlo   = (short*)(ws + OFF_HLO);
    short* xn    = (short*)(ws + OFF_XN);
    float* rowsum = ws + OFF_RS;
    float* diag   = ws + OFF_DG;
    short* rcdh  = (short*)(ws + OFF_RCDH);
    short* rcdl  = (short*)(ws + OFF_RCDL);
    float* ubias  = ws + OFF_UB;
    float* dbias  = ws + OFF_DB;
    float* U      = ws + OFF_U;
    float* V      = ws + OFF_V;
    float* D      = ws + OFF_D;
    short* sb    = (short*)(ws + OFF_SB);

    prep_kernel<<<912, 256, 0, stream>>>(w1, w2, w3, coefs, ws);

    for (int l = 0; l < LL; ++l) {
        mlp_kernel<<<NPOS/64, 256, 0, stream>>>(
            (l == 0) ? x : nullptr, (l == 0) ? nullptr : xn, mask,
            b1 + l*HH, b2 + l*HH, b3 + l*CC,
            sb + (long)l*HH*CC, sb + 24576 + (long)l*HH*HH, sb + 73728 + (long)l*CC*HH,
            hhi, hlo);
        reduce_kernel<<<BB*NN, 256, 0, stream>>>(hhi, hlo, rowsum, diag, rcdh, rcdl);
        tt_kernel<<<BB, 256, 0, stream>>>(rowsum, diag, coefs, l, ubias, dbias);
        uvd_kernel<<<16, 256, 0, stream>>>(rcdh, rcdl,
            sb + 147456 + (long)l*36864, sb + 258048 + (long)l*36864,
            ubias, dbias, U, V, D);
        eq_kernel<<<dim3(NN/8, NN/8, BB), 256, 0, stream>>>(
            hhi, hlo, mask,
            sb + 98304 + (long)l*CC*CC, sb + 110592 + (long)l*CC*CC,
            sb + 122880 + (long)l*CC*CC, sb + 135168 + (long)l*CC*CC,
            U, V, D, bias + l*CC, idb + l*CC,
            (l == LL-1) ? out : nullptr, (l == LL-1) ? nullptr : xn);
    }
}

// Round 5
// 300.227 us; speedup vs baseline: 1.3447x; 1.3447x over previous
//
#include <hip/hip_runtime.h>

#define BB 8
#define NN 128
#define CC 64
#define LL 3
#define HH 128
#define NEG 0.01f
#define NPOS (BB*NN*NN)   // 131072

typedef __attribute__((ext_vector_type(8))) short shortx8;   // 8 bf16 = 4 VGPRs
typedef __attribute__((ext_vector_type(4))) float f32x4;

// ---- workspace layout (float offsets) ----
#define OFF_HHI   0L          // h hi: 131072*64 shorts = 4194304 floats
#define OFF_HLO   4194304L    // h lo
#define OFF_XN    8388608L    // inter-layer x (bf16): 4194304 floats
#define OFF_RS    12582912L   // rowsum fp32 [1024][64]
#define OFF_DG    12648448L   // diag fp32 [1024][64]
#define OFF_RCDH  12713984L   // RCD hi [1024][192] shorts = 98304 floats
#define OFF_RCDL  12812288L
#define OFF_UB    12910592L   // Ubias [8][64]
#define OFF_DB    12911104L   // Dbias [8][64]
#define OFF_U     12911616L   // [1024][64]
#define OFF_V     12977152L
#define OFF_D     13042688L
#define OFF_SB    13108224L   // bf16 const region (shorts)
// sb short offsets: wb1@0 (L*128*64), wb2@24576 (L*128*128), wb3@73728 (L*64*128),
//   c9h@98304, c9l@110592, c10h@122880, c10l@135168 (each L*64*64, [l][s][d]),
//   Kh@147456, Kl@258048 (each L*192*192, [l][out][k])

__device__ __forceinline__ float leaky(float v) { return v >= 0.f ? v : NEG * v; }

__device__ __forceinline__ short f2bf(float f) {   // RNE float -> bf16
    unsigned u = __builtin_bit_cast(unsigned, f);
    u += 0x7fff + ((u >> 16) & 1);
    return (short)(u >> 16);
}
__device__ __forceinline__ float bf2f(short s) {
    unsigned u = ((unsigned)(unsigned short)s) << 16;
    return __builtin_bit_cast(float, u);
}
__device__ __forceinline__ unsigned pkf(float a, float b) {  // two f32 -> packed bf16x2
    return (unsigned)(unsigned short)f2bf(a) | ((unsigned)(unsigned short)f2bf(b) << 16);
}
__device__ __forceinline__ unsigned pks(short a, short b) {
    return (unsigned)(unsigned short)a | ((unsigned)(unsigned short)b << 16);
}

// ---------------- prep: bf16 weights, split c9/c10 [s][d], split K-matrix [out][k] ----------------
__global__ void prep_kernel(const float* __restrict__ w1, const float* __restrict__ w2,
                            const float* __restrict__ w3, const float* __restrict__ coefs,
                            float* __restrict__ ws) {
    long idx = (long)blockIdx.x * 256 + threadIdx.x;
    short* sb = (short*)(ws + OFF_SB);
    if (idx < 24576) {                       // wb1[l][h][c]
        sb[idx] = f2bf(w1[idx]);
    } else if (idx < 73728) {                // wb2[l][h][k]
        sb[idx] = f2bf(w2[idx - 24576]);
    } else if (idx < 98304) {                // wb3[l][c][k]
        sb[idx] = f2bf(w3[idx - 73728]);
    } else if (idx < 110592) {               // c9 hi/lo [l][s][d]
        long r = idx - 98304; int l = (int)(r / 4096); int q = (int)(r % 4096);
        int s = q >> 6, d = q & 63;
        float v = coefs[(((long)l*CC + d)*CC + s)*15 + 9];
        short hi = f2bf(v);
        sb[98304 + r]  = hi;
        sb[110592 + r] = f2bf(v - bf2f(hi));
    } else if (idx < 122880) {               // c10 hi/lo [l][s][d]
        long r = idx - 110592; int l = (int)(r / 4096); int q = (int)(r % 4096);
        int s = q >> 6, d = q & 63;
        float v = coefs[(((long)l*CC + d)*CC + s)*15 + 10];
        short hi = f2bf(v);
        sb[122880 + r] = hi;
        sb[135168 + r] = f2bf(v - bf2f(hi));
    } else if (idx < 233472) {               // Kbig hi/lo [l][out 192][k 192]
        long r = idx - 122880;
        int l = (int)(r / 36864); int q = (int)(r % 36864);
        int o = q / 192, k = q % 192;
        int wo = o >> 6, s = o & 63, wk = k >> 6, d = k & 63;
        const int sel[3][3] = {{5,6,11},{7,8,12},{3,2,0}};
        float v = coefs[(((long)l*CC + d)*CC + s)*15 + sel[wo][wk]];
        short hi = f2bf(v);
        sb[147456 + r] = hi;
        sb[258048 + r] = f2bf(v - bf2f(hi));
    }
}

// ---------------- MFMA fused 3-stage MLP (swapped operands: W = A-frag, x = B-frag) ------------
__global__ __launch_bounds__(256, 4) void mlp_kernel(
    const float* __restrict__ xf, const short* __restrict__ xb,
    const float* __restrict__ mask,
    const float* __restrict__ b1, const float* __restrict__ b2, const float* __restrict__ b3,
    const short* __restrict__ wb1, const short* __restrict__ wb2, const short* __restrict__ wb3,
    short* __restrict__ hhi, short* __restrict__ hlo)
{
    __shared__ __align__(16) char lds[40960];
    const int t = threadIdx.x;
    const int lane = t & 63;
    const int w = t >> 6;
    const int arow = lane & 15;
    const int kgrp = lane >> 4;
    const long pos0 = (long)blockIdx.x * 64;

    if (xb == nullptr) {
        const int row = t >> 2, q = t & 3;
        const float4* src = (const float4*)(xf + (pos0 + row)*CC + q*16);
        short sv[16];
        #pragma unroll
        for (int i = 0; i < 4; ++i) {
            float4 v = src[i];
            sv[i*4+0] = f2bf(v.x); sv[i*4+1] = f2bf(v.y);
            sv[i*4+2] = f2bf(v.z); sv[i*4+3] = f2bf(v.w);
        }
        const int swz = (row & 7) << 4;
        *(shortx8*)(&lds[row*128 + ((q*32 +  0) ^ swz)]) = *(shortx8*)(&sv[0]);
        *(shortx8*)(&lds[row*128 + ((q*32 + 16) ^ swz)]) = *(shortx8*)(&sv[8]);
        __syncthreads();
    }

    // ---- stage 1 ----
    {
        f32x4 acc[2][4];
        #pragma unroll
        for (int of = 0; of < 2; ++of)
            #pragma unroll
            for (int pf = 0; pf < 4; ++pf) acc[of][pf] = (f32x4){0.f,0.f,0.f,0.f};
        #pragma unroll
        for (int kk = 0; kk < 2; ++kk) {
            shortx8 bx[4];
            #pragma unroll
            for (int pf = 0; pf < 4; ++pf) {
                if (xb) {
                    bx[pf] = *(const shortx8*)(xb + (pos0 + pf*16 + arow)*CC + kk*32 + kgrp*8);
                } else {
                    const int p = pf*16 + arow;
                    bx[pf] = *(const shortx8*)(&lds[p*128 + ((kk*64 + kgrp*16) ^ ((p & 7) << 4))]);
                }
            }
            #pragma unroll
            for (int of = 0; of < 2; ++of) {
                const shortx8 a = *(const shortx8*)(wb1 + (long)(w*32 + of*16 + arow)*CC + kk*32 + kgrp*8);
                #pragma unroll
                for (int pf = 0; pf < 4; ++pf)
                    acc[of][pf] = __builtin_amdgcn_mfma_f32_16x16x32_bf16(a, bx[pf], acc[of][pf], 0, 0, 0);
            }
        }
        #pragma unroll
        for (int of = 0; of < 2; ++of) {
            const int o0 = w*32 + of*16 + kgrp*4;
            const float4 bv = *(const float4*)(b1 + o0);
            #pragma unroll
            for (int pf = 0; pf < 4; ++pf) {
                const int p = pf*16 + arow;
                unsigned u0 = pkf(leaky(acc[of][pf][0] + bv.x), leaky(acc[of][pf][1] + bv.y));
                unsigned u1 = pkf(leaky(acc[of][pf][2] + bv.z), leaky(acc[of][pf][3] + bv.w));
                *(uint2*)(&lds[8192 + p*256 + ((o0*2) ^ ((p & 7) << 4))]) = make_uint2(u0, u1);
            }
        }
    }
    __syncthreads();

    // ---- stage 2 ----
    {
        f32x4 acc[2][4];
        #pragma unroll
        for (int of = 0; of < 2; ++of)
            #pragma unroll
            for (int pf = 0; pf < 4; ++pf) acc[of][pf] = (f32x4){0.f,0.f,0.f,0.f};
        #pragma unroll
        for (int kk = 0; kk < 4; ++kk) {
            shortx8 bx[4];
            #pragma unroll
            for (int pf = 0; pf < 4; ++pf) {
                const int p = pf*16 + arow;
                bx[pf] = *(const shortx8*)(&lds[8192 + p*256 + ((kk*64 + kgrp*16) ^ ((p & 7) << 4))]);
            }
            #pragma unroll
            for (int of = 0; of < 2; ++of) {
                const shortx8 a = *(const shortx8*)(wb2 + (long)(w*32 + of*16 + arow)*HH + kk*32 + kgrp*8);
                #pragma unroll
                for (int pf = 0; pf < 4; ++pf)
                    acc[of][pf] = __builtin_amdgcn_mfma_f32_16x16x32_bf16(a, bx[pf], acc[of][pf], 0, 0, 0);
            }
        }
        #pragma unroll
        for (int of = 0; of < 2; ++of) {
            const int o0 = w*32 + of*16 + kgrp*4;
            const float4 bv = *(const float4*)(b2 + o0);
            #pragma unroll
            for (int pf = 0; pf < 4; ++pf) {
                const int p = pf*16 + arow;
                unsigned u0 = pkf(leaky(acc[of][pf][0] + bv.x), leaky(acc[of][pf][1] + bv.y));
                unsigned u1 = pkf(leaky(acc[of][pf][2] + bv.z), leaky(acc[of][pf][3] + bv.w));
                *(uint2*)(&lds[24576 + p*256 + ((o0*2) ^ ((p & 7) << 4))]) = make_uint2(u0, u1);
            }
        }
    }
    __syncthreads();

    // ---- stage 3: direct split-bf16 global store ----
    {
        f32x4 acc[4];
        #pragma unroll
        for (int pf = 0; pf < 4; ++pf) acc[pf] = (f32x4){0.f,0.f,0.f,0.f};
        #pragma unroll
        for (int kk = 0; kk < 4; ++kk) {
            const shortx8 a = *(const shortx8*)(wb3 + (long)(w*16 + arow)*HH + kk*32 + kgrp*8);
            #pragma unroll
            for (int pf = 0; pf < 4; ++pf) {
                const int p = pf*16 + arow;
                const shortx8 bx = *(const shortx8*)(&lds[24576 + p*256 + ((kk*64 + kgrp*16) ^ ((p & 7) << 4))]);
                acc[pf] = __builtin_amdgcn_mfma_f32_16x16x32_bf16(a, bx, acc[pf], 0, 0, 0);
            }
        }
        const int o0 = w*16 + kgrp*4;
        const float4 bv = *(const float4*)(b3 + o0);
        #pragma unroll
        for (int pf = 0; pf < 4; ++pf) {
            const int p = pf*16 + arow;
            const long pos = pos0 + p;
            const float mv = mask[pos];
            short hi[4], lo[4];
            float vals[4] = {acc[pf][0] + bv.x, acc[pf][1] + bv.y, acc[pf][2] + bv.z, acc[pf][3] + bv.w};
            #pragma unroll
            for (int r = 0; r < 4; ++r) {
                float v = leaky(vals[r]) * mv;
                hi[r] = f2bf(v);
                lo[r] = f2bf(v - bf2f(hi[r]));
            }
            *(uint2*)(hhi + pos*CC + o0) = make_uint2(pks(hi[0], hi[1]), pks(hi[2], hi[3]));
            *(uint2*)(hlo + pos*CC + o0) = make_uint2(pks(lo[0], lo[1]), pks(lo[2], lo[3]));
        }
    }
}

// ---------------- vectorized reductions: colsum/rowsum/diag ----------------
__global__ __launch_bounds__(256) void reduce_kernel(const short* __restrict__ hhi,
                                                     const short* __restrict__ hlo,
                                                     float* __restrict__ rowsum,
                                                     float* __restrict__ diag,
                                                     short* __restrict__ rcdh,
                                                     short* __restrict__ rcdl) {
    const int br = blockIdx.x;            // n*128 + r
    const int n = br >> 7, r = br & 127;
    const int t = threadIdx.x;
    const int cq = (t & 15) * 4;          // channel quad
    const int g = t >> 4;                 // 16 groups
    __shared__ float red[16][64];
    const long rowbase = ((long)(n*NN + r) * NN) * CC;

    // row pass: sum over j
    float s0 = 0.f, s1 = 0.f, s2 = 0.f, s3 = 0.f;
    for (int j = g; j < NN; j += 16) {
        const long idx = rowbase + (long)j*CC + cq;
        uint2 uh = *(const uint2*)(hhi + idx);
        uint2 ul = *(const uint2*)(hlo + idx);
        s0 += bf2f((short)uh.x) + bf2f((short)ul.x);
        s1 += bf2f((short)(uh.x >> 16)) + bf2f((short)(ul.x >> 16));
        s2 += bf2f((short)uh.y) + bf2f((short)ul.y);
        s3 += bf2f((short)(uh.y >> 16)) + bf2f((short)(ul.y >> 16));
    }
    red[g][cq] = s0; red[g][cq+1] = s1; red[g][cq+2] = s2; red[g][cq+3] = s3;
    __syncthreads();
    if (t < 64) {
        float rs = 0.f;
        #pragma unroll
        for (int k = 0; k < 16; ++k) rs += red[k][t];
        rowsum[(long)br*CC + t] = rs;
        short h = f2bf(rs);
        rcdh[(long)br*192 + 64 + t] = h;
        rcdl[(long)br*192 + 64 + t] = f2bf(rs - bf2f(h));
    }
    __syncthreads();

    // col pass: sum over i
    const long colbase = ((long)n*NN*NN + r) * CC;
    s0 = s1 = s2 = s3 = 0.f;
    for (int i = g; i < NN; i += 16) {
        const long idx = colbase + (long)i*NN*CC + cq;
        uint2 uh = *(const uint2*)(hhi + idx);
        uint2 ul = *(const uint2*)(hlo + idx);
        s0 += bf2f((short)uh.x) + bf2f((short)ul.x);
        s1 += bf2f((short)(uh.x >> 16)) + bf2f((short)(ul.x >> 16));
        s2 += bf2f((short)uh.y) + bf2f((short)ul.y);
        s3 += bf2f((short)(uh.y >> 16)) + bf2f((short)(ul.y >> 16));
    }
    red[g][cq] = s0; red[g][cq+1] = s1; red[g][cq+2] = s2; red[g][cq+3] = s3;
    __syncthreads();
    if (t < 64) {
        float cs = 0.f;
        #pragma unroll
        for (int k = 0; k < 16; ++k) cs += red[k][t];
        short h = f2bf(cs);
        rcdh[(long)br*192 + t] = h;
        rcdl[(long)br*192 + t] = f2bf(cs - bf2f(h));
        const long didx = rowbase + (long)r*CC + t;
        float dg = bf2f(hhi[didx]) + bf2f(hlo[didx]);
        diag[(long)br*CC + t] = dg;
        short hd = f2bf(dg);
        rcdh[(long)br*192 + 128 + t] = hd;
        rcdl[(long)br*192 + 128 + t] = f2bf(dg - bf2f(hd));
    }
}

// ---------------- trace/total -> per-n biases for U and D ----------------
__global__ __launch_bounds__(256) void tt_kernel(const float* __restrict__ rowsum,
                                                 const float* __restrict__ diag,
                                                 const float* __restrict__ coefs, int layer,
                                                 float* __restrict__ ubias,
                                                 float* __restrict__ dbias) {
    const int n = blockIdx.x;
    const int t = threadIdx.x, c = t & 63, g = t >> 6;
    __shared__ float ra[4][64], rb[4][64];
    __shared__ float trS[64], ttS[64];
    float a = 0.f, b = 0.f;
    for (int i = g; i < NN; i += 4) {
        a += rowsum[((long)n*NN + i)*CC + c];
        b += diag[((long)n*NN + i)*CC + c];
    }
    ra[g][c] = a; rb[g][c] = b;
    __syncthreads();
    if (t < 64) {
        ttS[c] = ra[0][c] + ra[1][c] + ra[2][c] + ra[3][c];
        trS[c] = rb[0][c] + rb[1][c] + rb[2][c] + rb[3][c];
    }
    __syncthreads();
    if (t < 128) {
        const int which = t >> 6, s = t & 63;
        const float* cf = coefs + (long)layer*CC*CC*15;
        float acc = 0.f;
        for (int d = 0; d < CC; ++d) {
            const float* cds = cf + ((long)d*CC + s)*15;
            if (which == 0) acc += cds[13]*trS[d] + cds[14]*ttS[d];
            else            acc += cds[1]*trS[d] + cds[4]*ttS[d];
        }
        if (which == 0) ubias[n*CC + s] = acc;
        else            dbias[n*CC + s] = acc;
    }
}

// ---------------- U/V/D via MFMA ----------------
__global__ __launch_bounds__(256) void uvd_kernel(
    const short* __restrict__ rcdh, const short* __restrict__ rcdl,
    const short* __restrict__ kh, const short* __restrict__ kl,
    const float* __restrict__ ubias, const float* __restrict__ dbias,
    float* __restrict__ U, float* __restrict__ V, float* __restrict__ D)
{
    const int t = threadIdx.x, lane = t & 63, w = t >> 6;
    const int arow = lane & 15, kgrp = lane >> 4;
    const int r0 = blockIdx.x * 64;
    f32x4 acc[3][4];
    #pragma unroll
    for (int o = 0; o < 3; ++o)
        #pragma unroll
        for (int pf = 0; pf < 4; ++pf) acc[o][pf] = (f32x4){0.f,0.f,0.f,0.f};
    #pragma unroll
    for (int kk = 0; kk < 6; ++kk) {
        shortx8 bh[4], bl[4];
        #pragma unroll
        for (int pf = 0; pf < 4; ++pf) {
            const long off = (long)(r0 + pf*16 + arow)*192 + kk*32 + kgrp*8;
            bh[pf] = *(const shortx8*)(rcdh + off);
            bl[pf] = *(const shortx8*)(rcdl + off);
        }
        #pragma unroll
        for (int o = 0; o < 3; ++o) {
            const long aoff = (long)((w*3 + o)*16 + arow)*192 + kk*32 + kgrp*8;
            const shortx8 ah = *(const shortx8*)(kh + aoff);
            const shortx8 al = *(const shortx8*)(kl + aoff);
            #pragma unroll
            for (int pf = 0; pf < 4; ++pf) {
                acc[o][pf] = __builtin_amdgcn_mfma_f32_16x16x32_bf16(ah, bh[pf], acc[o][pf], 0, 0, 0);
                acc[o][pf] = __builtin_amdgcn_mfma_f32_16x16x32_bf16(ah, bl[pf], acc[o][pf], 0, 0, 0);
                acc[o][pf] = __builtin_amdgcn_mfma_f32_16x16x32_bf16(al, bh[pf], acc[o][pf], 0, 0, 0);
            }
        }
    }
    #pragma unroll
    for (int o = 0; o < 3; ++o) {
        const int o16 = (w*3 + o)*16;
        const int o0 = o16 + kgrp*4;
        #pragma unroll
        for (int pf = 0; pf < 4; ++pf) {
            const long rr = r0 + pf*16 + arow;
            const int n = (int)(rr >> 7);
            float4 a = make_float4(acc[o][pf][0], acc[o][pf][1], acc[o][pf][2], acc[o][pf][3]);
            if (o16 < 64) {
                const float4 ub = *(const float4*)(ubias + n*CC + o0);
                a.x += ub.x; a.y += ub.y; a.z += ub.z; a.w += ub.w;
                *(float4*)(U + rr*CC + o0) = a;
            } else if (o16 < 128) {
                *(float4*)(V + rr*CC + (o0 - 64)) = a;
            } else {
                const float4 db = *(const float4*)(dbias + n*CC + (o0 - 128));
                a.x += db.x; a.y += db.y; a.z += db.z; a.w += db.w;
                *(float4*)(D + rr*CC + (o0 - 128)) = a;
            }
        }
    }
}

// ---------------- Eq2to2: symmetric pair-block, LDS-staged, each h element fetched once ---------
// Block (pair, n): tiles (it,jt) and (jt,it), it >= jt.
// LDS planes (8KB each): Ah@0, Al@8192, Mh@16384, Ml@24576.
//   A row p  = h[n, i0+(p>>3), j0+(p&7)]   (granule-XOR swizzled, 128B rows)
//   M row p  = h[n, j0+(p&7), i0+(p>>3)]
// out-A index p -> position (i0+(p>>3), j0+(p&7)): c9*A[p] + c10*M[p]
// out-M index p -> position (j0+(p&7), i0+(p>>3)): c9*M[p] + c10*A[p]   (skip when it==jt)
__global__ __launch_bounds__(256, 4) void eq_kernel(
    const short* __restrict__ hhi, const short* __restrict__ hlo,
    const float* __restrict__ mask,
    const short* __restrict__ c9h, const short* __restrict__ c9l,
    const short* __restrict__ c10h, const short* __restrict__ c10l,
    const float* __restrict__ U, const float* __restrict__ V, const float* __restrict__ D,
    const float* __restrict__ bias, const float* __restrict__ idbias,
    float* __restrict__ outf, short* __restrict__ outb)
{
    __shared__ __align__(16) char lds[32768];
    const int t = threadIdx.x, lane = t & 63, w = t >> 6;
    const int arow = lane & 15, kgrp = lane >> 4;
    const int n = blockIdx.y;
    const int pr = blockIdx.x;
    int it = (int)((sqrtf(8.f*pr + 1.f) - 1.f)*0.5f);
    while ((it+1)*(it+2)/2 <= pr) ++it;
    while (it*(it+1)/2 > pr) --it;
    const int jt = pr - it*(it+1)/2;      // jt <= it
    const int i0 = it*8, j0 = jt*8;

    // ---- stage both tiles (hi/lo), coalesced 32B loads, swizzled 16B ds_writes ----
    {
        const int row = t >> 2, q = t & 3;
        const long posA = ((long)n*NN + i0 + (row >> 3))*NN + (j0 + (row & 7));
        const long posM = ((long)n*NN + j0 + (row & 7))*NN + (i0 + (row >> 3));
        const short* sAh = hhi + posA*CC + q*16;
        const short* sAl = hlo + posA*CC + q*16;
        const short* sMh = hhi + posM*CC + q*16;
        const short* sMl = hlo + posM*CC + q*16;
        shortx8 v0 = *(const shortx8*)(sAh);
        shortx8 v1 = *(const shortx8*)(sAh + 8);
        shortx8 v2 = *(const shortx8*)(sAl);
        shortx8 v3 = *(const shortx8*)(sAl + 8);
        shortx8 v4 = *(const shortx8*)(sMh);
        shortx8 v5 = *(const shortx8*)(sMh + 8);
        shortx8 v6 = *(const shortx8*)(sMl);
        shortx8 v7 = *(const shortx8*)(sMl + 8);
        const int swz = (row & 7) << 4;
        const int d0 = row*128 + ((q*32) ^ swz);
        const int d1 = row*128 + ((q*32 + 16) ^ swz);
        *(shortx8*)(&lds[d0]) = v0;          *(shortx8*)(&lds[d1]) = v1;
        *(shortx8*)(&lds[8192 + d0]) = v2;   *(shortx8*)(&lds[8192 + d1]) = v3;
        *(shortx8*)(&lds[16384 + d0]) = v4;  *(shortx8*)(&lds[16384 + d1]) = v5;
        *(shortx8*)(&lds[24576 + d0]) = v6;  *(shortx8*)(&lds[24576 + d1]) = v7;
    }
    __syncthreads();

    const int s0 = w*16;
    f32x4 accA[4], accM[4];
    #pragma unroll
    for (int pf = 0; pf < 4; ++pf) { accA[pf] = (f32x4){0.f,0.f,0.f,0.f}; accM[pf] = (f32x4){0.f,0.f,0.f,0.f}; }

    #pragma unroll
    for (int kk = 0; kk < 2; ++kk) {
        const long co = (long)(s0 + arow)*CC + kk*32 + kgrp*8;
        const shortx8 a9h  = *(const shortx8*)(c9h  + co);
        const shortx8 a9l  = *(const shortx8*)(c9l  + co);
        const shortx8 a10h = *(const shortx8*)(c10h + co);
        const shortx8 a10l = *(const shortx8*)(c10l + co);
        #pragma unroll
        for (int pf = 0; pf < 4; ++pf) {
            const int p = pf*16 + arow;
            const int off = (kk*64 + kgrp*16) ^ ((p & 7) << 4);
            const shortx8 Ah = *(const shortx8*)(&lds[p*128 + off]);
            const shortx8 Al = *(const shortx8*)(&lds[8192 + p*128 + off]);
            const shortx8 Mh = *(const shortx8*)(&lds[16384 + p*128 + off]);
            const shortx8 Ml = *(const shortx8*)(&lds[24576 + p*128 + off]);
            accA[pf] = __builtin_amdgcn_mfma_f32_16x16x32_bf16(a9h,  Ah, accA[pf], 0, 0, 0);
            accA[pf] = __builtin_amdgcn_mfma_f32_16x16x32_bf16(a9h,  Al, accA[pf], 0, 0, 0);
            accA[pf] = __builtin_amdgcn_mfma_f32_16x16x32_bf16(a9l,  Ah, accA[pf], 0, 0, 0);
            accA[pf] = __builtin_amdgcn_mfma_f32_16x16x32_bf16(a10h, Mh, accA[pf], 0, 0, 0);
            accA[pf] = __builtin_amdgcn_mfma_f32_16x16x32_bf16(a10h, Ml, accA[pf], 0, 0, 0);
            accA[pf] = __builtin_amdgcn_mfma_f32_16x16x32_bf16(a10l, Mh, accA[pf], 0, 0, 0);
            accM[pf] = __builtin_amdgcn_mfma_f32_16x16x32_bf16(a9h,  Mh, accM[pf], 0, 0, 0);
            accM[pf] = __builtin_amdgcn_mfma_f32_16x16x32_bf16(a9h,  Ml, accM[pf], 0, 0, 0);
            accM[pf] = __builtin_amdgcn_mfma_f32_16x16x32_bf16(a9l,  Mh, accM[pf], 0, 0, 0);
            accM[pf] = __builtin_amdgcn_mfma_f32_16x16x32_bf16(a10h, Ah, accM[pf], 0, 0, 0);
            accM[pf] = __builtin_amdgcn_mfma_f32_16x16x32_bf16(a10h, Al, accM[pf], 0, 0, 0);
            accM[pf] = __builtin_amdgcn_mfma_f32_16x16x32_bf16(a10l, Ah, accM[pf], 0, 0, 0);
        }
    }

    const int sc = s0 + kgrp*4;
    const float4 bv = *(const float4*)(bias + sc);
    #pragma unroll
    for (int pf = 0; pf < 4; ++pf) {
        const int p = pf*16 + arow;
        // out-A
        {
            const int pi = i0 + (p >> 3), pj = j0 + (p & 7);
            const long pix = ((long)n*NN + pi)*NN + pj;
            const float4 u4 = *(const float4*)(U + ((long)n*NN + pi)*CC + sc);
            const float4 v4 = *(const float4*)(V + ((long)n*NN + pj)*CC + sc);
            float vv[4];
            vv[0] = accA[pf][0] + u4.x + v4.x + bv.x;
            vv[1] = accA[pf][1] + u4.y + v4.y + bv.y;
            vv[2] = accA[pf][2] + u4.z + v4.z + bv.z;
            vv[3] = accA[pf][3] + u4.w + v4.w + bv.w;
            if (it == jt && pi == pj) {
                const float4 d4  = *(const float4*)(D + ((long)n*NN + pi)*CC + sc);
                const float4 db4 = *(const float4*)(idbias + sc);
                vv[0] += d4.x + db4.x; vv[1] += d4.y + db4.y;
                vv[2] += d4.z + db4.z; vv[3] += d4.w + db4.w;
            }
            const float mv = mask[pix];
            #pragma unroll
            for (int r = 0; r < 4; ++r) vv[r] = leaky(vv[r]) * mv;
            if (outf) *(float4*)(outf + pix*CC + sc) = make_float4(vv[0], vv[1], vv[2], vv[3]);
            else      *(uint2*)(outb + pix*CC + sc) = make_uint2(pkf(vv[0], vv[1]), pkf(vv[2], vv[3]));
        }
        // out-M (mirror tile; disjoint from out-A when it != jt)
        if (it != jt) {
            const int pi = j0 + (p & 7), pj = i0 + (p >> 3);
            const long pix = ((long)n*NN + pi)*NN + pj;
            const float4 u4 = *(const float4*)(U + ((long)n*NN + pi)*CC + sc);
            const float4 v4 = *(const float4*)(V + ((long)n*NN + pj)*CC + sc);
            float vv[4];
            vv[0] = accM[pf][0] + u4.x + v4.x + bv.x;
            vv[1] = accM[pf][1] + u4.y + v4.y + bv.y;
            vv[2] = accM[pf][2] + u4.z + v4.z + bv.z;
            vv[3] = accM[pf][3] + u4.w + v4.w + bv.w;
            const float mv = mask[pix];
            #pragma unroll
            for (int r = 0; r < 4; ++r) vv[r] = leaky(vv[r]) * mv;
            if (outf) *(float4*)(outf + pix*CC + sc) = make_float4(vv[0], vv[1], vv[2], vv[3]);
            else      *(uint2*)(outb + pix*CC + sc) = make_uint2(pkf(vv[0], vv[1]), pkf(vv[2], vv[3]));
        }
    }
}

extern "C" void kernel_launch(void* const* d_in, const int* in_sizes, int n_in,
                              void* d_out, int out_size, void* d_ws, size_t ws_size,
                              hipStream_t stream) {
    const float* x     = (const float*)d_in[0];
    const float* mask  = (const float*)d_in[1];
    const float* w1    = (const float*)d_in[2];
    const float* b1    = (const float*)d_in[3];
    const float* w2    = (const float*)d_in[4];
    const float* b2    = (const float*)d_in[5];
    const float* w3    = (const float*)d_in[6];
    const float* b3    = (const float*)d_in[7];
    const float* coefs = (const float*)d_in[8];
    const float* bias  = (const float*)d_in[9];
    const float* idb   = (const float*)d_in[10];
    float* out = (float*)d_out;
    float* ws  = (float*)d_ws;

    short* hhi    = (short*)(ws + OFF_HHI);
    short* hlo    = (short*)(ws + OFF_HLO);
    short* xn     = (short*)(ws + OFF_XN);
    float* rowsum = ws + OFF_RS;
    float* diag   = ws + OFF_DG;
    short* rcdh   = (short*)(ws + OFF_RCDH);
    short* rcdl   = (short*)(ws + OFF_RCDL);
    float* ubias  = ws + OFF_UB;
    float* dbias  = ws + OFF_DB;
    float* U      = ws + OFF_U;
    float* V      = ws + OFF_V;
    float* D      = ws + OFF_D;
    short* sb     = (short*)(ws + OFF_SB);

    prep_kernel<<<912, 256, 0, stream>>>(w1, w2, w3, coefs, ws);

    for (int l = 0; l < LL; ++l) {
        mlp_kernel<<<NPOS/64, 256, 0, stream>>>(
            (l == 0) ? x : nullptr, (l == 0) ? nullptr : xn, mask,
            b1 + l*HH, b2 + l*HH, b3 + l*CC,
            sb + (long)l*HH*CC, sb + 24576 + (long)l*HH*HH, sb + 73728 + (long)l*CC*HH,
            hhi, hlo);
        reduce_kernel<<<BB*NN, 256, 0, stream>>>(hhi, hlo, rowsum, diag, rcdh, rcdl);
        tt_kernel<<<BB, 256, 0, stream>>>(rowsum, diag, coefs, l, ubias, dbias);
        uvd_kernel<<<16, 256, 0, stream>>>(rcdh, rcdl,
            sb + 147456 + (long)l*36864, sb + 258048 + (long)l*36864,
            ubias, dbias, U, V, D);
        eq_kernel<<<dim3(136, BB), 256, 0, stream>>>(
            hhi, hlo, mask,
            sb + 98304 + (long)l*CC*CC, sb + 110592 + (long)l*CC*CC,
            sb + 122880 + (long)l*CC*CC, sb + 135168 + (long)l*CC*CC,
            U, V, D, bias + l*CC, idb + l*CC,
            (l == LL-1) ? out : nullptr, (l == LL-1) ? nullptr : xn);
    }
}